// Round 1
// baseline (405.193 us; speedup 1.0000x reference)
//
#include <hip/hip_runtime.h>
#include <math.h>

// Masked attention fwd, B=8, Sq=Sk=2048, D=128, fp32 in/out.
// Flash-attention with bf16 hi/lo split MFMA (3x mfma per product => ~fp32 accuracy).

typedef short bf16x8 __attribute__((ext_vector_type(8)));
typedef float f32x4 __attribute__((ext_vector_type(4)));
typedef unsigned short u16x4 __attribute__((ext_vector_type(4)));

#define MFMA16 __builtin_amdgcn_mfma_f32_16x16x32_bf16
#define DSX(x, pat) __int_as_float(__builtin_amdgcn_ds_swizzle(__float_as_int(x), (pat)))

namespace {
constexpr int SQn = 2048, SKn = 2048, DH = 128;
constexpr int QB = 64, KBLK = 64, NSTEP = SKn / KBLK;

__device__ __forceinline__ unsigned short f2bf(float f) {
    union { float f; unsigned u; } x; x.f = f;
    unsigned r = x.u + 0x7FFFu + ((x.u >> 16) & 1u);   // RNE
    return (unsigned short)(r >> 16);
}
__device__ __forceinline__ float bf2f(unsigned short h) {
    union { unsigned u; float f; } x; x.u = ((unsigned)h) << 16;
    return x.f;
}
}  // namespace

// LDS map (byte offsets), all rows are 256B, swizzle: off ^= ((row&15)<<4)
//  khi[buf]  : buf*32768          [64 kv rows][128 d] bf16
//  klo[buf]  : buf*32768 + 16384
//  vT [buf]  : 65536 + buf*32768  [128 d rows][ hi:64 kv | lo:64 kv ] bf16
//  p32[wave] : 131072 + w*4096    [16 qrows][64 kv] f32
__global__ __launch_bounds__(256, 1) void fattn_kernel(
    const float* __restrict__ Q, const float* __restrict__ K,
    const float* __restrict__ V, const float* __restrict__ M,
    float* __restrict__ O)
{
    __shared__ __align__(16) char smem[147456];
    const int bid = blockIdx.x;
    const int b  = bid & 7;        // batch == bid%8 -> one batch per XCD (L2 locality)
    const int qt = bid >> 3;
    const int tid = threadIdx.x;
    const int lane = tid & 63;
    const int w = tid >> 6;        // wave 0..3, owns q-rows w*16..w*16+15
    const int m16 = lane & 15;
    const int g = lane >> 4;

    const float* Qw = Q + ((size_t)(b * SQn + qt * QB + w * 16)) * DH;
    const float* Kb = K + (size_t)b * SKn * DH;
    const float* Vb = V + (size_t)b * SKn * DH;
    const float* Mw = M + ((size_t)(b * SQn + qt * QB + w * 16)) * SKn;
    float* Ow = O + ((size_t)(b * SQn + qt * QB + w * 16)) * DH;

    // ---- Q fragments (A-layout: lane = 16*(k/8)+m), hi/lo split ----
    bf16x8 qh[4], ql[4];
#pragma unroll
    for (int c = 0; c < 4; ++c) {
        const float* qp = Qw + m16 * DH + c * 32 + g * 8;
        const float4 a0 = *(const float4*)qp;
        const float4 a1 = *(const float4*)(qp + 4);
        float xs[8] = {a0.x, a0.y, a0.z, a0.w, a1.x, a1.y, a1.z, a1.w};
#pragma unroll
        for (int j = 0; j < 8; ++j) {
            unsigned short h = f2bf(xs[j]);
            qh[c][j] = (short)h;
            ql[c][j] = (short)f2bf(xs[j] - bf2f(h));
        }
    }

    float4 kreg[8], vreg[8];
    float mk[4][4], mk2[4][4] = {};

    auto stage_load = [&](int t) {
        const size_t base = (size_t)t * KBLK * DH;
#pragma unroll
        for (int i = 0; i < 8; ++i) {
            const int f4 = i * 256 + tid;
            const int row = f4 >> 5, c4 = f4 & 31;
            kreg[i] = *(const float4*)(Kb + base + row * DH + c4 * 4);
            vreg[i] = *(const float4*)(Vb + base + row * DH + c4 * 4);
        }
    };

    auto stage_write = [&](int buf) {
        char* khp = smem + buf * 32768;
        char* klp = khp + 16384;
        char* vbp = smem + 65536 + buf * 32768;
#pragma unroll
        for (int i = 0; i < 8; ++i) {
            const int f4 = i * 256 + tid;
            const int row = f4 >> 5, c4 = f4 & 31;
            const int sw = (row & 15) << 4;
            float xs[4] = {kreg[i].x, kreg[i].y, kreg[i].z, kreg[i].w};
            u16x4 h4, l4;
#pragma unroll
            for (int j = 0; j < 4; ++j) {
                unsigned short h = f2bf(xs[j]);
                h4[j] = h;
                l4[j] = f2bf(xs[j] - bf2f(h));
            }
            const int koff = row * 256 + ((c4 * 8) ^ sw);
            *(u16x4*)(khp + koff) = h4;
            *(u16x4*)(klp + koff) = l4;
            float vs[4] = {vreg[i].x, vreg[i].y, vreg[i].z, vreg[i].w};
#pragma unroll
            for (int j = 0; j < 4; ++j) {   // transpose into vT[d][kv]
                const int d = c4 * 4 + j;
                const int sv = (d & 15) << 4;
                char* rowp = vbp + d * 256;
                unsigned short h = f2bf(vs[j]);
                unsigned short l = f2bf(vs[j] - bf2f(h));
                *(unsigned short*)(rowp + ((row * 2) ^ sv)) = h;
                *(unsigned short*)(rowp + ((128 + row * 2) ^ sv)) = l;
            }
        }
    };

    auto mload = [&](int t, float (*dst)[4]) {
        const int kv0 = t * KBLK;
#pragma unroll
        for (int r = 0; r < 4; ++r) {
            const size_t rb = (size_t)(4 * g + r) * SKn + kv0 + m16;
#pragma unroll
            for (int nt = 0; nt < 4; ++nt) dst[r][nt] = Mw[rb + nt * 16];
        }
    };

    f32x4 o_[8];
#pragma unroll
    for (int nt = 0; nt < 8; ++nt) o_[nt] = 0.f;
    float mrow[4] = {-INFINITY, -INFINITY, -INFINITY, -INFINITY};
    float lrow[4] = {0.f, 0.f, 0.f, 0.f};

    stage_load(0);
    mload(0, mk);
    stage_write(0);
    __syncthreads();

    for (int t = 0; t < NSTEP; ++t) {
        const int cur = t & 1;
        const bool more = (t + 1 < NSTEP);
        if (more) stage_load(t + 1);          // prefetch next K/V tile into regs

        // ---- S = Q K^T (B-layout: lane = 16*(d/8)+kv) ----
        const char* khp = smem + cur * 32768;
        const char* klp = khp + 16384;
        f32x4 sf[4];
#pragma unroll
        for (int nt = 0; nt < 4; ++nt) sf[nt] = 0.f;
#pragma unroll
        for (int c = 0; c < 4; ++c) {
            const int coff = c * 64 + g * 16;
#pragma unroll
            for (int nt = 0; nt < 4; ++nt) {
                const int row = nt * 16 + m16;
                const int off = row * 256 + (coff ^ ((row & 15) << 4));
                bf16x8 bh = *(const bf16x8*)(khp + off);
                bf16x8 bl = *(const bf16x8*)(klp + off);
                sf[nt] = MFMA16(qh[c], bh, sf[nt], 0, 0, 0);
                sf[nt] = MFMA16(qh[c], bl, sf[nt], 0, 0, 0);
                sf[nt] = MFMA16(ql[c], bh, sf[nt], 0, 0, 0);
            }
        }

        if (more) mload(t + 1, mk2);          // prefetch next mask tile (full-iter cover)

        // ---- masked online softmax (D-frag row = 4g+r, col = nt*16+m16) ----
        char* pbp = smem + 131072 + w * 4096;
        float corr[4];
#pragma unroll
        for (int r = 0; r < 4; ++r) {
            float s0 = sf[0][r] * mk[r][0];
            float s1 = sf[1][r] * mk[r][1];
            float s2 = sf[2][r] * mk[r][2];
            float s3 = sf[3][r] * mk[r][3];
            float mx = fmaxf(fmaxf(s0, s1), fmaxf(s2, s3));
            mx = fmaxf(mx, DSX(mx, 0x041F));
            mx = fmaxf(mx, DSX(mx, 0x081F));
            mx = fmaxf(mx, DSX(mx, 0x101F));
            mx = fmaxf(mx, DSX(mx, 0x201F));
            const float mn = fmaxf(mrow[r], mx);
            const float cr = __expf(mrow[r] - mn);
            corr[r] = cr;
            mrow[r] = mn;
            const float p0 = __expf(s0 - mn);
            const float p1 = __expf(s1 - mn);
            const float p2 = __expf(s2 - mn);
            const float p3 = __expf(s3 - mn);
            float ps = (p0 + p1) + (p2 + p3);
            ps += DSX(ps, 0x041F);
            ps += DSX(ps, 0x081F);
            ps += DSX(ps, 0x101F);
            ps += DSX(ps, 0x201F);
            lrow[r] = lrow[r] * cr + ps;
            const int prow = 4 * g + r;
            char* pr = pbp + prow * 256;
            const int swp = (prow & 15) << 4;
            *(float*)(pr + ((m16 * 4) ^ swp)) = p0;
            *(float*)(pr + (((m16 + 16) * 4) ^ swp)) = p1;
            *(float*)(pr + (((m16 + 32) * 4) ^ swp)) = p2;
            *(float*)(pr + (((m16 + 48) * 4) ^ swp)) = p3;
        }
#pragma unroll
        for (int nt = 0; nt < 8; ++nt)
#pragma unroll
            for (int r = 0; r < 4; ++r) o_[nt][r] *= corr[r];

        // ---- O += P V  (A = P from per-wave LDS, B = vT) ----
        const char* vbp = smem + 65536 + cur * 32768;
        const char* prd = pbp + m16 * 256;
        const int swp = (m16 & 15) << 4;
#pragma unroll
        for (int ch = 0; ch < 2; ++ch) {
            const int pc = ch * 128 + g * 32;
            f32x4 pA = *(const f32x4*)(prd + (pc ^ swp));
            f32x4 pB = *(const f32x4*)(prd + ((pc + 16) ^ swp));
            float px[8] = {pA[0], pA[1], pA[2], pA[3], pB[0], pB[1], pB[2], pB[3]};
            bf16x8 ph, pl;
#pragma unroll
            for (int j = 0; j < 8; ++j) {
                unsigned short h = f2bf(px[j]);
                ph[j] = (short)h;
                pl[j] = (short)f2bf(px[j] - bf2f(h));
            }
            const int kvo = ch * 64 + g * 16;
#pragma unroll
            for (int nt = 0; nt < 8; ++nt) {
                const int d = nt * 16 + m16;
                const char* rowp = vbp + d * 256;
                const int sv = (d & 15) << 4;
                bf16x8 vh = *(const bf16x8*)(rowp + (kvo ^ sv));
                bf16x8 vl = *(const bf16x8*)(rowp + ((128 + kvo) ^ sv));
                o_[nt] = MFMA16(ph, vh, o_[nt], 0, 0, 0);
                o_[nt] = MFMA16(ph, vl, o_[nt], 0, 0, 0);
                o_[nt] = MFMA16(pl, vh, o_[nt], 0, 0, 0);
            }
        }

        if (more) stage_write(cur ^ 1);       // write next tile into other buffer
        __syncthreads();                      // one barrier per KV step
        if (more) {
#pragma unroll
            for (int r = 0; r < 4; ++r)
#pragma unroll
                for (int nt = 0; nt < 4; ++nt) mk[r][nt] = mk2[r][nt];
        }
    }

    // ---- epilogue: normalize and store ----
#pragma unroll
    for (int r = 0; r < 4; ++r) {
        const float inv = 1.f / lrow[r];
        float* orow = Ow + (4 * g + r) * DH + m16;
#pragma unroll
        for (int nt = 0; nt < 8; ++nt) orow[nt * 16] = o_[nt][r] * inv;
    }
}

extern "C" void kernel_launch(void* const* d_in, const int* in_sizes, int n_in,
                              void* d_out, int out_size, void* d_ws, size_t ws_size,
                              hipStream_t stream) {
    (void)in_sizes; (void)n_in; (void)out_size; (void)d_ws; (void)ws_size;
    const float* q = (const float*)d_in[0];
    const float* k = (const float*)d_in[1];
    const float* v = (const float*)d_in[2];
    const float* m = (const float*)d_in[3];
    float* o = (float*)d_out;
    fattn_kernel<<<dim3(256), dim3(256), 0, stream>>>(q, k, v, m, o);
}

// Round 3
// 274.259 us; speedup vs baseline: 1.4774x; 1.4774x over previous
//
#include <hip/hip_runtime.h>
#include <math.h>

// Masked attention fwd, B=8, Sq=Sk=2048, D=128, fp32 in/out.
// Flash-attention, swapped QK^T (S^T = K*Q^T) so P stays in-lane for PV.
// bf16 hi/lo split MFMA (3 mfma per product => ~fp32 accuracy).
// 8 waves/block: 2 KV-groups x 4 q-waves, flash-merge at end.

typedef short bf16x8 __attribute__((ext_vector_type(8)));
typedef short short4v __attribute__((ext_vector_type(4)));
typedef float f32x4 __attribute__((ext_vector_type(4)));
typedef unsigned short u16x4 __attribute__((ext_vector_type(4)));

#define MFMA16 __builtin_amdgcn_mfma_f32_16x16x32_bf16

namespace {
constexpr int SKn = 2048, DH = 128;
constexpr int QB = 64;
constexpr int NSTEP = 32;  // per group: 1024 kv / 32 per tile

__device__ __forceinline__ unsigned short f2bf(float f) {
    union { float f; unsigned u; } x; x.f = f;
    unsigned r = x.u + 0x7FFFu + ((x.u >> 16) & 1u);   // RNE
    return (unsigned short)(r >> 16);
}
__device__ __forceinline__ float bf2f(unsigned short h) {
    union { unsigned u; float f; } x; x.u = ((unsigned)h) << 16;
    return x.f;
}
}  // namespace

// LDS map: group g2 at g2*65536; slot b at +b*32768:
//   Khi +0      [32 kv][128 d] bf16, 256B rows, swz: col ^ ((kv&15)<<4)
//   Klo +8192
//   Vhi +16384  [128 d][32 kv] bf16, 64B rows,  swz: col ^ ((d&7)<<3)
//   Vlo +24576
// Epilogue merge scratch (after final barrier): per g1-wave ws:
//   O1 at ws*8448 (16 rows x 528B), m/l float2 at 33792 + ws*128 + q*8
__global__ __launch_bounds__(512, 2) void fattn_kernel(
    const float* __restrict__ Q, const float* __restrict__ K,
    const float* __restrict__ V, const float* __restrict__ M,
    float* __restrict__ O)
{
    __shared__ __align__(16) char smem[131072];
    const int bid = blockIdx.x;
    const int b  = bid & 7;        // batch per XCD for K/V/M L2 locality
    const int qt = bid >> 3;
    const int tid = threadIdx.x;
    const int lane = tid & 63;
    const int w = tid >> 6;        // 0..7
    const int g2 = w >> 2;         // kv group 0/1
    const int wq = w & 3;          // q sub-tile, rows wq*16..+15
    const int gtid = tid & 255;    // thread id within group
    const int m16 = lane & 15;
    const int g = lane >> 4;

    char* slotbase = smem + g2 * 65536;

    const float* Qw = Q + ((size_t)(b * 2048 + qt * QB + wq * 16)) * DH;
    const float* Kb = K + (size_t)b * SKn * DH;
    const float* Vb = V + (size_t)b * SKn * DH;
    const float* Mw = M + ((size_t)(b * 2048 + qt * QB + wq * 16)) * SKn;
    float* Ow = O + ((size_t)(b * 2048 + qt * QB + wq * 16)) * DH;

    // ---- Q fragments (B-operand of S^T: lane(g,m16) holds Q[m16][c*32+g*8+e]) ----
    bf16x8 qh[4], ql[4];
#pragma unroll
    for (int c = 0; c < 4; ++c) {
        const float* qp = Qw + m16 * DH + c * 32 + g * 8;
        f32x4 a0 = *(const f32x4*)qp;
        f32x4 a1 = *(const f32x4*)(qp + 4);
#pragma unroll
        for (int j = 0; j < 8; ++j) {
            float x = (j < 4) ? a0[j] : a1[j - 4];
            unsigned short h = f2bf(x);
            qh[c][j] = (short)h;
            ql[c][j] = (short)f2bf(x - bf2f(h));
        }
    }

    f32x4 kreg[4], vreg[4];
    f32x4 mreg[2], mreg2[2];
    const int krow = gtid >> 5, kc4 = gtid & 31;   // K stage: coalesced
    const int vkv = gtid & 31,  vc8 = gtid >> 5;   // V stage: row-strided

    auto kv_of = [&](int t) { return (2 * t + g2) * 32; };

    auto stage_load = [&](int t) {
        const int kv0 = kv_of(t);
#pragma unroll
        for (int i = 0; i < 4; ++i)
            kreg[i] = *(const f32x4*)(Kb + (size_t)(kv0 + i * 8 + krow) * DH + kc4 * 4);
#pragma unroll
        for (int i = 0; i < 4; ++i)
            vreg[i] = *(const f32x4*)(Vb + (size_t)(kv0 + vkv) * DH + (vc8 + i * 8) * 4);
    };

    auto stage_write = [&](int bufsel) {
        char* Khi = slotbase + bufsel * 32768;
        char* Klo = Khi + 8192;
        char* Vhi = Khi + 16384;
        char* Vlo = Khi + 24576;
#pragma unroll
        for (int i = 0; i < 4; ++i) {
            const int row = i * 8 + krow;
            u16x4 h4, l4;
#pragma unroll
            for (int j = 0; j < 4; ++j) {
                unsigned short h = f2bf(kreg[i][j]);
                h4[j] = h;
                l4[j] = f2bf(kreg[i][j] - bf2f(h));
            }
            const int off = row * 256 + ((kc4 * 8) ^ ((row & 15) << 4));
            *(u16x4*)(Khi + off) = h4;
            *(u16x4*)(Klo + off) = l4;
        }
#pragma unroll
        for (int i = 0; i < 4; ++i) {
#pragma unroll
            for (int j = 0; j < 4; ++j) {
                const int d = (vc8 + i * 8) * 4 + j;
                const int off = d * 64 + ((vkv * 2) ^ ((d & 7) << 3));
                unsigned short h = f2bf(vreg[i][j]);
                *(unsigned short*)(Vhi + off) = h;
                *(unsigned short*)(Vlo + off) = f2bf(vreg[i][j] - bf2f(h));
            }
        }
    };

    auto mload = [&](int t, f32x4* dst) {
        const int kv0 = kv_of(t);
#pragma unroll
        for (int nt = 0; nt < 2; ++nt)
            dst[nt] = *(const f32x4*)(Mw + (size_t)m16 * SKn + kv0 + nt * 16 + 4 * g);
    };

    f32x4 o_[8];
#pragma unroll
    for (int nt = 0; nt < 8; ++nt) o_[nt] = 0.f;
    float mrow = -INFINITY, lrow = 0.f;

    stage_load(0);
    mload(0, mreg);
    stage_write(0);
    __syncthreads();

    for (int t = 0; t < NSTEP; ++t) {
        const int cur = t & 1;
        const bool more = (t + 1 < NSTEP);
        if (more) stage_load(t + 1);

        // ---- S^T = K * Q^T : A = K-frag (LDS), B = Q-frag (regs) ----
        const char* Khi = slotbase + cur * 32768;
        const char* Klo = Khi + 8192;
        f32x4 sT[2];
        sT[0] = 0.f; sT[1] = 0.f;
#pragma unroll
        for (int c = 0; c < 4; ++c) {
#pragma unroll
            for (int nt = 0; nt < 2; ++nt) {
                const int row = nt * 16 + m16;
                const int off = row * 256 + ((c * 64 + g * 16) ^ ((row & 15) << 4));
                bf16x8 ah = *(const bf16x8*)(Khi + off);
                bf16x8 al = *(const bf16x8*)(Klo + off);
                sT[nt] = MFMA16(ah, qh[c], sT[nt], 0, 0, 0);
                sT[nt] = MFMA16(ah, ql[c], sT[nt], 0, 0, 0);
                sT[nt] = MFMA16(al, qh[c], sT[nt], 0, 0, 0);
            }
        }

        if (more) mload(t + 1, mreg2);

        // ---- masked online softmax: lane(g,m16) owns q=m16, kv=nt*16+4g+r ----
        float p[2][4];
        float mx = -INFINITY;
#pragma unroll
        for (int nt = 0; nt < 2; ++nt)
#pragma unroll
            for (int r = 0; r < 4; ++r) {
                p[nt][r] = sT[nt][r] * mreg[nt][r];
                mx = fmaxf(mx, p[nt][r]);
            }
        mx = fmaxf(mx, __shfl_xor(mx, 16));
        mx = fmaxf(mx, __shfl_xor(mx, 32));
        const float mn = fmaxf(mrow, mx);
        const float corr = __expf(mrow - mn);
        mrow = mn;
        float ps = 0.f;
#pragma unroll
        for (int nt = 0; nt < 2; ++nt)
#pragma unroll
            for (int r = 0; r < 4; ++r) {
                p[nt][r] = __expf(p[nt][r] - mn);
                ps += p[nt][r];
            }
        ps += __shfl_xor(ps, 16);
        ps += __shfl_xor(ps, 32);
        lrow = lrow * corr + ps;

        // rescale O (O rows are q=4g+r -> fetch corr from lane with m16=4g+r)
        f32x4 corrO;
#pragma unroll
        for (int r = 0; r < 4; ++r) corrO[r] = __shfl(corr, 4 * g + r);
#pragma unroll
        for (int nt = 0; nt < 8; ++nt)
#pragma unroll
            for (int r = 0; r < 4; ++r) o_[nt][r] *= corrO[r];

        // ---- P fragments: A-elem e = p[e>>2][e&3]  (pi(k) permutation) ----
        bf16x8 ph, pl;
#pragma unroll
        for (int e = 0; e < 8; ++e) {
            const float x = p[e >> 2][e & 3];
            unsigned short h = f2bf(x);
            ph[e] = (short)h;
            pl[e] = (short)f2bf(x - bf2f(h));
        }

        // ---- O += P V : B-frag from vT, kv cols {4g..4g+3, 16+4g..+3} ----
        const char* Vhi = Khi + 16384;
        const char* Vlo = Khi + 24576;
#pragma unroll
        for (int nt = 0; nt < 8; ++nt) {
            const int d = nt * 16 + m16;
            const int sw = (d & 7) << 3;
            const int off1 = d * 64 + ((g * 8) ^ sw);
            const int off2 = d * 64 + ((32 + g * 8) ^ sw);
            short4v h1 = *(const short4v*)(Vhi + off1);
            short4v h2 = *(const short4v*)(Vhi + off2);
            short4v l1 = *(const short4v*)(Vlo + off1);
            short4v l2 = *(const short4v*)(Vlo + off2);
            bf16x8 vh = __builtin_shufflevector(h1, h2, 0, 1, 2, 3, 4, 5, 6, 7);
            bf16x8 vl = __builtin_shufflevector(l1, l2, 0, 1, 2, 3, 4, 5, 6, 7);
            o_[nt] = MFMA16(ph, vh, o_[nt], 0, 0, 0);
            o_[nt] = MFMA16(ph, vl, o_[nt], 0, 0, 0);
            o_[nt] = MFMA16(pl, vh, o_[nt], 0, 0, 0);
        }

        if (more) stage_write(cur ^ 1);
        __syncthreads();
        if (more) { mreg[0] = mreg2[0]; mreg[1] = mreg2[1]; }
    }

    // ---- flash merge of the two kv-groups ----
    if (g2 == 1) {
        char* ob = smem + wq * 8448;
#pragma unroll
        for (int nt = 0; nt < 8; ++nt)
#pragma unroll
            for (int r = 0; r < 4; ++r)
                *(float*)(ob + (4 * g + r) * 528 + (nt * 16 + m16) * 4) = o_[nt][r];
        if (g == 0)
            *(float2*)(smem + 33792 + wq * 128 + m16 * 8) = make_float2(mrow, lrow);
    }
    __syncthreads();
    if (g2 == 0) {
        const float2 ml1 = *(const float2*)(smem + 33792 + wq * 128 + m16 * 8);
        const float ms = fmaxf(mrow, ml1.x);
        const float e0 = __expf(mrow - ms);
        const float e1 = __expf(ml1.x - ms);
        const float inv = 1.f / (lrow * e0 + ml1.y * e1);
        const float a0 = e0 * inv, a1 = e1 * inv;
        f32x4 a0r, a1r;
#pragma unroll
        for (int r = 0; r < 4; ++r) {
            a0r[r] = __shfl(a0, 4 * g + r);
            a1r[r] = __shfl(a1, 4 * g + r);
        }
        const char* ob = smem + wq * 8448;
#pragma unroll
        for (int nt = 0; nt < 8; ++nt)
#pragma unroll
            for (int r = 0; r < 4; ++r) {
                const int d = nt * 16 + m16;
                const float o1 = *(const float*)(ob + (4 * g + r) * 528 + d * 4);
                Ow[(size_t)(4 * g + r) * DH + d] = o_[nt][r] * a0r[r] + o1 * a1r[r];
            }
    }
}

extern "C" void kernel_launch(void* const* d_in, const int* in_sizes, int n_in,
                              void* d_out, int out_size, void* d_ws, size_t ws_size,
                              hipStream_t stream) {
    (void)in_sizes; (void)n_in; (void)out_size; (void)d_ws; (void)ws_size;
    const float* q = (const float*)d_in[0];
    const float* k = (const float*)d_in[1];
    const float* v = (const float*)d_in[2];
    const float* m = (const float*)d_in[3];
    float* o = (float*)d_out;
    fattn_kernel<<<dim3(256), dim3(512), 0, stream>>>(q, k, v, m, o);
}